// Round 1
// baseline (3141.402 us; speedup 1.0000x reference)
//
#include <hip/hip_runtime.h>

// LSTM sliding-window scan, B=128, T=256, H=128, WIN=16, 240 windows.
// One block per batch element; thread j owns gate row j (W_hh row in VGPRs).
// h broadcast via LDS; c in registers of threads 0..127. Two barriers/step.

#define HH   128
#define GG   512   // 4*H
#define TT   256
#define WIN  16
#define NWIN 240   // T - WIN

__device__ __forceinline__ float sigm(float xv) {
    // 1/(1+exp(-x)) via v_exp_f32 + v_rcp_f32 (approx, ~1ulp — fine vs 7.6e-2 threshold)
    return __builtin_amdgcn_rcpf(1.0f + __expf(-xv));
}
__device__ __forceinline__ float tanh_fast(float xv) {
    // tanh(x) = 1 - 2/(exp(2x)+1); saturates correctly for |x| large (inf -> 1 / -1)
    return 1.0f - 2.0f * __builtin_amdgcn_rcpf(__expf(2.0f * xv) + 1.0f);
}

__global__ __launch_bounds__(GG, 2) void lstm_win_kernel(
    const float* __restrict__ x,
    const float* __restrict__ W_ih,
    const float* __restrict__ W_hh,
    const float* __restrict__ b_ih,
    const float* __restrict__ b_hh,
    const float* __restrict__ fc_W,
    const float* __restrict__ fc_b,
    float* __restrict__ out)
{
    const int b = blockIdx.x;   // batch element
    const int j = threadIdx.x;  // gate row 0..511: [0,128)=i [128,256)=f [256,384)=g [384,512)=o

    __shared__ float4 h4[HH / 4];     // hidden state (broadcast-read, conflict-free)
    __shared__ float  act_s[GG];      // activated gates for this step
    __shared__ float  xrow_s[TT];     // this batch's x row

    // --- preload: W_hh row j into 128 VGPRs, scalars ---
    float w[HH];
#pragma unroll
    for (int k4 = 0; k4 < HH / 4; ++k4) {
        float4 v = ((const float4*)(W_hh + j * HH))[k4];
        w[4*k4+0] = v.x; w[4*k4+1] = v.y; w[4*k4+2] = v.z; w[4*k4+3] = v.w;
    }
    const float wih  = W_ih[j];
    const float bias = b_ih[j] + b_hh[j];

    const float* xrow = x + b * TT;
    if (j < TT)  xrow_s[j] = xrow[j];
    if (j < HH)  ((float*)h4)[j] = 0.0f;
    if (j < WIN) out[b * TT + j] = xrow[j];   // prefix copy: out[:, :16] = x[:, :16]

    float c = 0.0f;                            // cell state (threads 0..127)
    float fcw0 = 0.0f, fcw1 = 0.0f, fcb = 0.0f;
    if (j < 64) { fcw0 = fc_W[j]; fcw1 = fc_W[j + 64]; fcb = fc_b[0]; }

    __syncthreads();

    for (int s = 0; s < NWIN; ++s) {
        for (int t = 0; t < WIN; ++t) {
            const float xt = xrow_s[s + t];
            // gates_j = x_t*W_ih[j] + b + dot(W_hh[j,:], h)
            float a0 = 0.f, a1 = 0.f, a2 = 0.f, a3 = 0.f;  // 4 chains: hide 4-cyc FMA latency
#pragma unroll
            for (int k4 = 0; k4 < HH / 4; ++k4) {
                float4 hv = h4[k4];            // uniform address -> LDS broadcast
                a0 = fmaf(w[4*k4+0], hv.x, a0);
                a1 = fmaf(w[4*k4+1], hv.y, a1);
                a2 = fmaf(w[4*k4+2], hv.z, a2);
                a3 = fmaf(w[4*k4+3], hv.w, a3);
            }
            const float gate = fmaf(xt, wih, bias) + ((a0 + a1) + (a2 + a3));
            const float a = (j >= 2*HH && j < 3*HH) ? tanh_fast(gate) : sigm(gate);
            act_s[j] = a;
            __syncthreads();                   // activations published
            if (j < HH) {
                const float ai = act_s[j];
                const float af = act_s[HH  + j];
                const float ag = act_s[2*HH + j];
                const float ao = act_s[3*HH + j];
                c = fmaf(af, c, ai * ag);
                ((float*)h4)[j] = ao * tanh_fast(c);
            }
            __syncthreads();                   // new h visible to all
        }
        // window output: leaky_relu(fc_W . h + fc_b, 0.3) — wave 0 only.
        // Safe vs next step: h4 is only rewritten after the next step's first
        // barrier, which wave 0 must also reach.
        if (j < 64) {
            const float* hs = (const float*)h4;
            float v = fmaf(fcw0, hs[j], fcw1 * hs[j + 64]);
            #pragma unroll
            for (int off = 32; off > 0; off >>= 1)
                v += __shfl_down(v, off, 64);
            if (j == 0) {
                const float r = v + fcb;
                out[b * TT + WIN + s] = (r >= 0.f) ? r : 0.3f * r;
            }
        }
    }
}

extern "C" void kernel_launch(void* const* d_in, const int* in_sizes, int n_in,
                              void* d_out, int out_size, void* d_ws, size_t ws_size,
                              hipStream_t stream) {
    const float* x    = (const float*)d_in[0];
    const float* W_ih = (const float*)d_in[1];
    const float* W_hh = (const float*)d_in[2];
    const float* b_ih = (const float*)d_in[3];
    const float* b_hh = (const float*)d_in[4];
    const float* fc_W = (const float*)d_in[5];
    const float* fc_b = (const float*)d_in[6];
    // d_in[7] = pred_fut (unused)
    float* out = (float*)d_out;

    lstm_win_kernel<<<dim3(128), dim3(GG), 0, stream>>>(
        x, W_ih, W_hh, b_ih, b_hh, fc_W, fc_b, out);
}

// Round 3
// 2395.421 us; speedup vs baseline: 1.3114x; 1.3114x over previous
//
#include <hip/hip_runtime.h>

// LSTM sliding-window scan, B=128, T=256, H=128, WIN=16, 240 windows.
// One block per batch; thread j owns gate row j. Weights packed fp16x2 in
// 64 VGPRs; h packed fp16x2 in LDS (broadcast reads); v_dot2_f32_f16 MACs
// with fp32 accumulate; c stays fp32 in registers of threads 0..127.

#define HH   128
#define GG   512   // 4*H
#define TT   256
#define WIN  16
#define NWIN 240   // T - WIN

typedef __fp16 half2v __attribute__((ext_vector_type(2)));

__device__ __forceinline__ float sigm(float xv) {
    return __builtin_amdgcn_rcpf(1.0f + __expf(-xv));
}
__device__ __forceinline__ float tanh_fast(float xv) {
    return 1.0f - 2.0f * __builtin_amdgcn_rcpf(__expf(2.0f * xv) + 1.0f);
}
__device__ __forceinline__ float fdot2(half2v a, half2v b, float c) {
#if __has_builtin(__builtin_amdgcn_fdot2)
    return __builtin_amdgcn_fdot2(a, b, c, false);   // v_dot2_f32_f16
#else
    return fmaf((float)a[0], (float)b[0], fmaf((float)a[1], (float)b[1], c));
#endif
}
__device__ __forceinline__ half2v f_as_h2(float f) { return __builtin_bit_cast(half2v, f); }
__device__ __forceinline__ float  h2_as_f(half2v h) { return __builtin_bit_cast(float, h); }

__global__ void __attribute__((amdgpu_flat_work_group_size(512, 512)))
               __attribute__((amdgpu_waves_per_eu(2, 2)))
lstm_win_kernel(
    const float* __restrict__ x,
    const float* __restrict__ W_ih,
    const float* __restrict__ W_hh,
    const float* __restrict__ b_ih,
    const float* __restrict__ b_hh,
    const float* __restrict__ fc_W,
    const float* __restrict__ fc_b,
    float* __restrict__ out)
{
    const int b = blockIdx.x;   // batch element
    const int j = threadIdx.x;  // gate row: [0,128)=i [128,256)=f [256,384)=g [384,512)=o

    __shared__ __align__(16) float h2_s[HH / 2];  // packed f16x2 hidden state
    __shared__ float act_s[GG];                   // activated gates
    __shared__ float xrow_s[TT];                  // this batch's x row

    // --- preload: W_hh row j packed to 64 half2 VGPRs ---
    half2v wp[HH / 2];
    {
        const float4* wr = (const float4*)(W_hh + j * HH);
#pragma unroll
        for (int i = 0; i < HH / 4; ++i) {
            float4 v = wr[i];
            wp[2*i]   = __builtin_amdgcn_cvt_pkrtz(v.x, v.y);
            wp[2*i+1] = __builtin_amdgcn_cvt_pkrtz(v.z, v.w);
        }
    }
    const float wih  = W_ih[j];
    const float bias = b_ih[j] + b_hh[j];

    const float* xrow = x + b * TT;
    if (j < TT)     xrow_s[j] = xrow[j];
    if (j < HH/2)   h2_s[j] = 0.0f;               // h = 0 (packed zeros)
    if (j < WIN)    out[b * TT + j] = xrow[j];    // out[:, :16] = x[:, :16]

    float c = 0.0f;                               // cell state (threads 0..127)
    half2v fcpk = (half2v)0;                      // packed fc_W pair for thread j<64
    float  fcb  = 0.0f;
    if (j < 64) {
        fcpk = __builtin_amdgcn_cvt_pkrtz(fc_W[2*j], fc_W[2*j+1]);
        fcb  = fc_b[0];
    }

    __syncthreads();

    for (int s = 0; s < NWIN; ++s) {
        for (int t = 0; t < WIN; ++t) {
            const float xt = xrow_s[s + t];
            // gate_j = x_t*W_ih[j] + b + dot(W_hh[j,:], h)   (fp16 pairs, fp32 acc)
            float a0 = 0.f, a1 = 0.f, a2 = 0.f, a3 = 0.f;
            const float4* h4 = (const float4*)h2_s;
#pragma unroll
            for (int i = 0; i < HH / 8; ++i) {    // 16 iters: 4 pairs each
                float4 hv = h4[i];                // uniform addr -> LDS broadcast
                a0 = fdot2(wp[4*i+0], f_as_h2(hv.x), a0);
                a1 = fdot2(wp[4*i+1], f_as_h2(hv.y), a1);
                a2 = fdot2(wp[4*i+2], f_as_h2(hv.z), a2);
                a3 = fdot2(wp[4*i+3], f_as_h2(hv.w), a3);
            }
            const float gate = fmaf(xt, wih, bias) + ((a0 + a1) + (a2 + a3));
            const float a = (j >= 2*HH && j < 3*HH) ? tanh_fast(gate) : sigm(gate);
            act_s[j] = a;
            __syncthreads();                      // activations published
            if (j < HH) {
                const float ai = act_s[j];
                const float af = act_s[HH  + j];
                const float ag = act_s[2*HH + j];
                const float ao = act_s[3*HH + j];
                c = fmaf(af, c, ai * ag);
                const float hj = ao * tanh_fast(c);
                const float hp = __shfl_xor(hj, 1, 64);  // partner h (pair in-wave)
                if ((j & 1) == 0)                 // thread 2i packs (h_2i, h_2i+1)
                    h2_s[j >> 1] = h2_as_f(__builtin_amdgcn_cvt_pkrtz(hj, hp));
            }
            __syncthreads();                      // new h visible to all
        }
        // window output: leaky_relu(fc_W . h + fc_b, 0.3) — wave 0 only.
        // Safe: h2_s next rewritten only after the next step's first barrier,
        // which wave 0 must also reach.
        if (j < 64) {
            float v = fdot2(fcpk, f_as_h2(h2_s[j]), 0.0f);
#pragma unroll
            for (int off = 32; off > 0; off >>= 1)
                v += __shfl_down(v, off, 64);
            if (j == 0) {
                const float r = v + fcb;
                out[b * TT + WIN + s] = (r >= 0.f) ? r : 0.3f * r;
            }
        }
    }
}

extern "C" void kernel_launch(void* const* d_in, const int* in_sizes, int n_in,
                              void* d_out, int out_size, void* d_ws, size_t ws_size,
                              hipStream_t stream) {
    const float* x    = (const float*)d_in[0];
    const float* W_ih = (const float*)d_in[1];
    const float* W_hh = (const float*)d_in[2];
    const float* b_ih = (const float*)d_in[3];
    const float* b_hh = (const float*)d_in[4];
    const float* fc_W = (const float*)d_in[5];
    const float* fc_b = (const float*)d_in[6];
    // d_in[7] = pred_fut (unused)
    float* out = (float*)d_out;

    lstm_win_kernel<<<dim3(128), dim3(GG), 0, stream>>>(
        x, W_ih, W_hh, b_ih, b_hh, fc_W, fc_b, out);
}

// Round 4
// 1886.035 us; speedup vs baseline: 1.6656x; 1.2701x over previous
//
#include <hip/hip_runtime.h>

// LSTM sliding-window scan, B=128, T=256, H=128, WIN=16, 240 windows.
// One block per batch. Quad (4 lanes) owns one hidden unit: lane s of quad q
// computes gate rows {q, q+128, q+256, q+384} partial-dotted over h columns
// [32s, 32s+32). DPP quad_perm transpose-reduce -> lane s holds gate s of
// unit q; DPP quad-broadcast all-gathers the 4 activated gates so every lane
// updates c/h in-register. ONE barrier/step, h double-buffered fp16 in LDS.

#define HH   128
#define GG   512   // 4*H
#define TT   256
#define WIN  16
#define NWIN 240   // T - WIN

typedef __fp16 half2v __attribute__((ext_vector_type(2)));

// quad_perm DPP controls
#define XOR1 0xB1  // [1,0,3,2]
#define XOR2 0x4E  // [2,3,0,1]
#define BC0  0x00  // [0,0,0,0]
#define BC1  0x55  // [1,1,1,1]
#define BC2  0xAA  // [2,2,2,2]
#define BC3  0xFF  // [3,3,3,3]

template<int CTRL>
__device__ __forceinline__ float dppf(float v) {
    return __builtin_bit_cast(float,
        __builtin_amdgcn_update_dpp(0, __builtin_bit_cast(int, v),
                                    CTRL, 0xF, 0xF, true));
}

__device__ __forceinline__ float fdot2(half2v a, half2v b, float c) {
#if __has_builtin(__builtin_amdgcn_fdot2)
    return __builtin_amdgcn_fdot2(a, b, c, false);   // v_dot2_f32_f16
#else
    return fmaf((float)a[0], (float)b[0], fmaf((float)a[1], (float)b[1], c));
#endif
}
__device__ __forceinline__ half2v f_as_h2(float f) { return __builtin_bit_cast(half2v, f); }

__device__ __forceinline__ float tanh_fast(float xv) {
    return 1.0f - 2.0f * __builtin_amdgcn_rcpf(__expf(2.0f * xv) + 1.0f);
}

__global__ void __attribute__((amdgpu_flat_work_group_size(512, 512)))
               __attribute__((amdgpu_waves_per_eu(2, 2)))
lstm_win_kernel(
    const float* __restrict__ x,
    const float* __restrict__ W_ih,
    const float* __restrict__ W_hh,
    const float* __restrict__ b_ih,
    const float* __restrict__ b_hh,
    const float* __restrict__ fc_W,
    const float* __restrict__ fc_b,
    float* __restrict__ out)
{
    const int b  = blockIdx.x;
    const int j  = threadIdx.x;
    const int q  = j >> 2;      // hidden unit 0..127
    const int s4 = j & 3;       // col segment / gate index (i,f,g,o)

    __shared__ __align__(16) __fp16 hbuf[2][HH];  // double-buffered hidden state
    __shared__ float xrow_s[TT];

    // --- preload weights: 4 rows x 32-col segment, packed fp16x2 (64 VGPRs) ---
    half2v wp[4][16];
#pragma unroll
    for (int m = 0; m < 4; ++m) {
        const float* wr = W_hh + (q + 128 * m) * HH + 32 * s4;
#pragma unroll
        for (int i = 0; i < 8; ++i) {
            float4 v = ((const float4*)wr)[i];
            wp[m][2*i]   = __builtin_amdgcn_cvt_pkrtz(v.x, v.y);
            wp[m][2*i+1] = __builtin_amdgcn_cvt_pkrtz(v.z, v.w);
        }
    }
    const int   row  = 128 * s4 + q;          // gate row this lane owns post-reduce
    const float wih  = W_ih[row];
    const float bias = b_ih[row] + b_hh[row];
    const float Ac   = (s4 == 2) ? 2.0f : 1.0f;   // tanh = 2*sigm(2x)-1
    const float Bc   = (s4 == 2) ? 2.0f : 1.0f;
    const float Cc   = (s4 == 2) ? -1.0f : 0.0f;

    const float* xrow = x + b * TT;
    if (j < TT)  xrow_s[j] = xrow[j];
    if (j < HH) { hbuf[0][j] = (__fp16)0.f; hbuf[1][j] = (__fp16)0.f; }
    if (j < WIN) out[b * TT + j] = xrow[j];   // out[:, :16] = x[:, :16]

    float c = 0.0f;                           // cell state, replicated per quad
    half2v fcpk = (half2v)0;
    float  fcb  = 0.0f;
    if (j < 64) {
        fcpk = __builtin_amdgcn_cvt_pkrtz(fc_W[2*j], fc_W[2*j+1]);
        fcb  = fc_b[0];
    }

    __syncthreads();

    const bool b0 = s4 & 1;
    const bool b1 = (s4 >> 1) & 1;

    for (int s = 0; s < NWIN; ++s) {
#pragma unroll
        for (int t = 0; t < WIN; ++t) {
            const float xt = xrow_s[s + t];
            const float4* h4 = (const float4*)(&hbuf[t & 1][0]) + 4 * s4;
            float p0 = 0.f, p1 = 0.f, p2 = 0.f, p3 = 0.f;
#pragma unroll
            for (int i = 0; i < 4; ++i) {
                float4 hv = h4[i];
                half2v ha = f_as_h2(hv.x), hb = f_as_h2(hv.y);
                half2v hc = f_as_h2(hv.z), hd = f_as_h2(hv.w);
                p0 = fdot2(wp[0][4*i+0], ha, p0); p1 = fdot2(wp[1][4*i+0], ha, p1);
                p2 = fdot2(wp[2][4*i+0], ha, p2); p3 = fdot2(wp[3][4*i+0], ha, p3);
                p0 = fdot2(wp[0][4*i+1], hb, p0); p1 = fdot2(wp[1][4*i+1], hb, p1);
                p2 = fdot2(wp[2][4*i+1], hb, p2); p3 = fdot2(wp[3][4*i+1], hb, p3);
                p0 = fdot2(wp[0][4*i+2], hc, p0); p1 = fdot2(wp[1][4*i+2], hc, p1);
                p2 = fdot2(wp[2][4*i+2], hc, p2); p3 = fdot2(wp[3][4*i+2], hc, p3);
                p0 = fdot2(wp[0][4*i+3], hd, p0); p1 = fdot2(wp[1][4*i+3], hd, p1);
                p2 = fdot2(wp[2][4*i+3], hd, p2); p3 = fdot2(wp[3][4*i+3], hd, p3);
            }
            // quad transpose-reduce (DPP, no LDS): lane s4 -> full sum of row m=s4
            float k0 = b0 ? p1 : p0, sd0 = b0 ? p0 : p1;
            float k1 = b0 ? p3 : p2, sd1 = b0 ? p2 : p3;
            float n0 = k0 + dppf<XOR1>(sd0);
            float n1 = k1 + dppf<XOR1>(sd1);
            float kk = b1 ? n1 : n0, sd2 = b1 ? n0 : n1;
            const float gate = (kk + dppf<XOR2>(sd2)) + fmaf(xt, wih, bias);
            // unified activation: sigm for s4 in {0,1,3}, tanh for s4==2
            const float act = fmaf(Ac,
                __builtin_amdgcn_rcpf(1.0f + __expf(-Bc * gate)), Cc);
            // quad all-gather of the 4 activated gates
            const float ai = dppf<BC0>(act);
            const float af = dppf<BC1>(act);
            const float ag = dppf<BC2>(act);
            const float ao = dppf<BC3>(act);
            c = fmaf(af, c, ai * ag);                 // replicated across quad
            const float ht = ao * tanh_fast(c);
            if (s4 == 0) hbuf[(t + 1) & 1][q] = (__fp16)ht;
            __syncthreads();                          // ONE barrier per step
        }
        // window output: leaky_relu(fc_W . h + fc_b, 0.3). h after t=15 is in
        // hbuf[0] (WIN even). Other waves only read hbuf[0]/write hbuf[1] until
        // the next barrier, which this wave must also reach -> race-free.
        if (j < 64) {
            const float hpair = ((const float*)&hbuf[0][0])[j];
            float v = fdot2(fcpk, f_as_h2(hpair), 0.0f);
#pragma unroll
            for (int off = 32; off > 0; off >>= 1)
                v += __shfl_down(v, off, 64);
            if (j == 0) {
                const float r = v + fcb;
                out[b * TT + WIN + s] = (r >= 0.f) ? r : 0.3f * r;
            }
        }
    }
}

extern "C" void kernel_launch(void* const* d_in, const int* in_sizes, int n_in,
                              void* d_out, int out_size, void* d_ws, size_t ws_size,
                              hipStream_t stream) {
    const float* x    = (const float*)d_in[0];
    const float* W_ih = (const float*)d_in[1];
    const float* W_hh = (const float*)d_in[2];
    const float* b_ih = (const float*)d_in[3];
    const float* b_hh = (const float*)d_in[4];
    const float* fc_W = (const float*)d_in[5];
    const float* fc_b = (const float*)d_in[6];
    float* out = (float*)d_out;

    lstm_win_kernel<<<dim3(128), dim3(GG), 0, stream>>>(
        x, W_ih, W_hh, b_ih, b_hh, fc_W, fc_b, out);
}